// Round 5
// baseline (271.647 us; speedup 1.0000x reference)
//
#include <hip/hip_runtime.h>
#include <stdint.h>

// BinaryLinearWscales: out[m,n] = wscale[n] * (x @ sign(W)^T)[m,n] + wbias[n] * rowsum(x)[m]
// M = B*S = 4096, N = DOUT = 4096, K = DIN = 4096.
// Round 10: two INDEPENDENT blocks per CU to fill the per-phase barrier gap.
//   Evidence (r7/r8/r9): phase time 1350-1444 cy invariant across serial /
//   pipelined / half-LDS-traffic structures; MFMA needs only 585 cy. The ~800cy
//   residue is issue+wait+barrier exposed because all waves on a SIMD share one
//   block's barrier. Fix (m114 mechanism): 128x256 block, 4 waves (1x4), 48 KB
//   LDS -> 2 blocks/CU with independent barrier schedules; 2 waves/SIMD from
//   DIFFERENT blocks overlap MFMA with stage/wait.
//   - BK=64 tiles (64 tiles, 2 phases each = 128 phases), 32B K-half slots
//   - slots: A[2buf][2kh] 4KB @0..16K; B[2buf][2kh] 8KB @16K..48K
//   - read-ahead register pipeline (lgkmcnt(6)); stage ring distance 2,
//     steady ENDSYNC = vmcnt(3)+barrier (3 loads/phase: A1+B2)
//   - 32B-row swizzle sw=(row>>2)&1 (uniform per-8-lane bank coverage)
//   - bijective XCD swizzle: 8x8 block square per XCD

#define MDIM 4096
#define NDIM 4096
#define KDIM 4096

typedef int int4v  __attribute__((ext_vector_type(4)));
typedef int int16v __attribute__((ext_vector_type(16)));

__device__ __forceinline__ int pack4_rn(float a, float b, float c, float d, float inv) {
  int ia = __float2int_rn(a * inv) & 0xff;
  int ib = __float2int_rn(b * inv) & 0xff;
  int ic = __float2int_rn(c * inv) & 0xff;
  int id = __float2int_rn(d * inv) & 0xff;
  return ia | (ib << 8) | (ic << 16) | (id << 24);
}

__device__ __forceinline__ int sgn8(float v) {
  return (v > 0.f) ? 1 : ((v < 0.f) ? 0xff : 0);
}

// ---------------- fused prep (UNCHANGED: isolates gemm delta) ----------------
__global__ __launch_bounds__(256) void prep_kernel(
    const float* __restrict__ x, const float* __restrict__ w,
    char* __restrict__ xq, char* __restrict__ wsg,
    float* __restrict__ xscale, float* __restrict__ sumx) {
  const int b = blockIdx.x;
  const int tid = threadIdx.x;
  if (b < MDIM) {
    const int row = b;
    const float4* xr = (const float4*)(x + (size_t)row * KDIM);
    float4 v[4];
    float s = 0.f, amax = 0.f;
#pragma unroll
    for (int u = 0; u < 4; ++u) {
      v[u] = xr[u * 256 + tid];
      s += v[u].x + v[u].y + v[u].z + v[u].w;
      amax = fmaxf(amax, fmaxf(fmaxf(fabsf(v[u].x), fabsf(v[u].y)),
                               fmaxf(fabsf(v[u].z), fabsf(v[u].w))));
    }
#pragma unroll
    for (int off = 32; off > 0; off >>= 1) {
      s += __shfl_down(s, off, 64);
      amax = fmaxf(amax, __shfl_down(amax, off, 64));
    }
    __shared__ float rs[4], rm[4], bcast;
    if ((tid & 63) == 0) { rs[tid >> 6] = s; rm[tid >> 6] = amax; }
    __syncthreads();
    if (tid == 0) {
      sumx[row] = rs[0] + rs[1] + rs[2] + rs[3];
      float mt = fmaxf(fmaxf(rm[0], rm[1]), fmaxf(rm[2], rm[3]));
      xscale[row] = mt * (1.f / 127.f);
      bcast = (mt > 0.f) ? 127.f / mt : 0.f;
    }
    __syncthreads();
    const float inv = bcast;
    int* xo = (int*)(xq + (size_t)row * KDIM);
#pragma unroll
    for (int u = 0; u < 4; ++u)
      xo[u * 256 + tid] = pack4_rn(v[u].x, v[u].y, v[u].z, v[u].w, inv);
  } else {
    const size_t base = (size_t)(b - MDIM) * (256 * 4);
    const float4* wr = (const float4*)w;
    int* wo = (int*)wsg;
#pragma unroll
    for (int u = 0; u < 4; ++u) {
      size_t i = base + u * 256 + tid;
      float4 v = wr[i];
      wo[i] = sgn8(v.x) | (sgn8(v.y) << 8) | (sgn8(v.z) << 16) | (sgn8(v.w) << 24);
    }
  }
}

// ---------------- 128x256, 4-wave 1x4, 2 blocks/CU, pipelined i8 GEMM ----------------
__global__ __launch_bounds__(256, 2) void gemm_bin_i8_2b(
    const char* __restrict__ A, const char* __restrict__ Bs,
    const float* __restrict__ wscale, const float* __restrict__ wbias,
    const float* __restrict__ xscale, const float* __restrict__ sumx,
    float* __restrict__ C) {
  // A slots: [0,16K) = (buf*2+kh)*4096 ; B slots: [16K,48K) = 16384+(buf*2+kh)*8192
  __shared__ __align__(16) char sm[49152];

  // bijective XCD swizzle: 512 blocks, 8 XCDs, each gets an 8bm x 8bn square
  const int bid = blockIdx.x;
  const int xcd = bid & 7, loc = bid >> 3;            // loc in [0,64)
  const int bm = (xcd >> 1) * 8 + (loc >> 3);         // [0,32)
  const int bn = (xcd & 1) * 8 + (loc & 7);           // [0,16)
  const int tm0 = bm * 128, tn0 = bn * 256;
  const int tid = threadIdx.x;
  const int lane = tid & 63, wave = tid >> 6;
  const int col32 = lane & 31, hl = lane >> 5;  // 32x32 operand: row/col = lane&31, k16-chunk = lane>>5
  const int wc = wave;                          // 1 x 4 wave grid, wave tile 128x64

  int16v acc[4][2];   // 4 M-subtiles x 2 N-subtiles of 32x32 -> 128 VGPRs
#pragma unroll
  for (int mi = 0; mi < 4; ++mi)
#pragma unroll
    for (int nj = 0; nj < 2; ++nj)
#pragma unroll
      for (int r = 0; r < 16; ++r) acc[mi][nj][r] = 0;

  // two static fragment register sets (phase-alternating read-ahead pipeline)
  int4v afA[4], bqA[2], afB[4], bqB[2];

  // ds_read offsets within a slot. 32B rows, 2 chunks of 16B; sw = (row>>2)&1.
  int aOff[4], bOff[2];
#pragma unroll
  for (int mi = 0; mi < 4; ++mi) {
    int row = mi * 32 + col32;                  // [0,128)
    aOff[mi] = row * 32 + ((hl ^ ((row >> 2) & 1)) & 1) * 16;
  }
#pragma unroll
  for (int nj = 0; nj < 2; ++nj) {
    int row = wc * 64 + nj * 32 + col32;        // [0,256)
    bOff[nj] = row * 32 + ((hl ^ ((row >> 2) & 1)) & 1) * 16;
  }

  // staging: A-half = 128 rows x 32B = 4KB (1 x 16B/thread);
  //          B-half = 256 rows x 32B = 8KB (2 x 16B/thread).
  // linear LDS dest u*16 (row=u>>1, phys=u&1) <- global chunk (u&1)^sw(row)
  const int rA = tid >> 1;
  const int cA = (tid & 1) ^ ((rA >> 2) & 1);
  const char* gA0 = A + (size_t)(tm0 + rA) * KDIM + cA * 16;
  const char* gBp[2];
#pragma unroll
  for (int q = 0; q < 2; ++q) {
    int u = tid + 256 * q;
    int row = u >> 1;
    int c = (u & 1) ^ ((row >> 2) & 1);
    gBp[q] = Bs + (size_t)(tn0 + row) * KDIM + c * 16;
  }
  const int ldA = tid * 16, ldB0 = tid * 16, ldB1 = 4096 + tid * 16;

#define STAGE3(BUF, KH, KOFS)                                                     \
  do {                                                                            \
    const int baseA_ = ((BUF) * 2 + (KH)) * 4096;                                 \
    const int baseB_ = 16384 + ((BUF) * 2 + (KH)) * 8192;                         \
    __builtin_amdgcn_global_load_lds(                                             \
        (const __attribute__((address_space(1))) void*)(gA0 + (KOFS)),            \
        (__attribute__((address_space(3))) void*)(sm + baseA_ + ldA), 16, 0, 0);  \
    __builtin_amdgcn_global_load_lds(                                             \
        (const __attribute__((address_space(1))) void*)(gBp[0] + (KOFS)),         \
        (__attribute__((address_space(3))) void*)(sm + baseB_ + ldB0), 16, 0, 0); \
    __builtin_amdgcn_global_load_lds(                                             \
        (const __attribute__((address_space(1))) void*)(gBp[1] + (KOFS)),         \
        (__attribute__((address_space(3))) void*)(sm + baseB_ + ldB1), 16, 0, 0); \
  } while (0)

// next-phase fragment reads into regset SET from slot (BUF,KS)
#define DSRD(SET, BUF, KS)                                                        \
  do {                                                                            \
    const int baseA_ = ((BUF) * 2 + (KS)) * 4096;                                 \
    const int baseB_ = 16384 + ((BUF) * 2 + (KS)) * 8192;                         \
    _Pragma("unroll") for (int mi_ = 0; mi_ < 4; ++mi_)                           \
        af##SET[mi_] = *(const int4v*)(sm + baseA_ + aOff[mi_]);                  \
    _Pragma("unroll") for (int nj_ = 0; nj_ < 2; ++nj_)                           \
        bq##SET[nj_] = *(const int4v*)(sm + baseB_ + bOff[nj_]);                  \
  } while (0)

#define MFMA8(SET)                                                                \
  do {                                                                            \
    __builtin_amdgcn_s_setprio(1);                                                \
    _Pragma("unroll") for (int mi_ = 0; mi_ < 4; ++mi_)                           \
        _Pragma("unroll") for (int nj_ = 0; nj_ < 2; ++nj_)                       \
            acc[mi_][nj_] = __builtin_amdgcn_mfma_i32_32x32x32_i8(                \
                af##SET[mi_], bq##SET[nj_], acc[mi_][nj_], 0, 0, 0);              \
    __builtin_amdgcn_s_setprio(0);                                                \
  } while (0)

// wait own 6 frags only: 6 newer (next phase's reads) may stay outstanding.
#define WAITL6                                                                    \
  do {                                                                            \
    asm volatile("s_waitcnt lgkmcnt(6)" ::: "memory");                            \
    __builtin_amdgcn_sched_barrier(0);                                            \
  } while (0)
#define WAITL0                                                                    \
  do {                                                                            \
    asm volatile("s_waitcnt lgkmcnt(0)" ::: "memory");                            \
    __builtin_amdgcn_sched_barrier(0);                                            \
  } while (0)

#define CKV3 asm volatile("s_waitcnt vmcnt(3)\n\ts_barrier" ::: "memory")
#define CKV0 asm volatile("s_waitcnt vmcnt(0)\n\ts_barrier" ::: "memory")

// phase: {read next frags -> NSET ; issue STAGE} || {wait own ; MFMA CSET} ; ENDSYNC
#define PHASEP(CSET, NSET, NBUF, NKS, STAGEOP, ENDSYNC)                           \
  do {                                                                            \
    DSRD(NSET, NBUF, NKS);                                                        \
    STAGEOP;                                                                      \
    WAITL6;                                                                       \
    MFMA8(CSET);                                                                  \
    ENDSYNC;                                                                      \
  } while (0)

// one K-tile (2 phases), tile TAU in buf BUF = TAU&1:
//   p0: compute k0 (set A), read-ahead (BUF,k1), stage k1(TAU+1) -> slot(BUF^1,1)
//   p1: compute k1 (set B), read-ahead (BUF^1,k0) = tile TAU+1 k0, stage k0(TAU+2) -> slot(BUF,0)
// steady outstanding entering p0 = 3 (k0(TAU+1)); p0's CKV3 drains it (p1 reads it
// ahead); p1's CKV3 drains k1(TAU+1) (p0 of TAU+1 reads it ahead).
#define TILE_MAIN(BUF, TAU)                                                       \
  do {                                                                            \
    PHASEP(A, B, BUF, 1, STAGE3((BUF) ^ 1, 1, ((TAU) + 1) * 64 + 32), CKV3);      \
    PHASEP(B, A, (BUF) ^ 1, 0, STAGE3(BUF, 0, ((TAU) + 2) * 64), CKV3);           \
  } while (0)

  // prologue: tile0 {k0,k1} + tile1 {k0}; vmcnt(3) proves tile0 landed,
  // keeps tile1-k0 in flight; pre-read phase-0 fragments.
  STAGE3(0, 0, 0);
  STAGE3(0, 1, 32);
  STAGE3(1, 0, 64);
  CKV3;
  DSRD(A, 0, 0);

  // tiles 0..61
#pragma unroll 1
  for (int t = 0; t < 62; t += 2) {
    TILE_MAIN(0, t);
    TILE_MAIN(1, t + 1);
  }

  // tail tile 62 (buf 0): stage only k1(63); CKV0 drains it before its read-ahead
  PHASEP(A, B, 0, 1, STAGE3(1, 1, 63 * 64 + 32), CKV3);
  PHASEP(B, A, 1, 0, (void)0, CKV0);
  // tail tile 63 (buf 1): compute only; no sync needed after p0 (no DMA pending)
  PHASEP(A, B, 1, 1, (void)0, (void)0);
  WAITL0;
  MFMA8(B);

#undef TILE_MAIN
#undef PHASEP
#undef CKV3
#undef CKV0
#undef WAITL6
#undef WAITL0
#undef MFMA8
#undef DSRD
#undef STAGE3

  // epilogue: C[m,n] = wscale[n]*xscale[m]*acc + wbias[n]*sumx[m]
  // 32x32 C/D layout (shape-determined, m74/m101): col = lane&31,
  // row = (reg&3) + 8*(reg>>2) + 4*(lane>>5)
  float wsv[2], wbv[2];
#pragma unroll
  for (int nj = 0; nj < 2; ++nj) {
    int n = tn0 + wc * 64 + nj * 32 + col32;
    wsv[nj] = wscale[n];
    wbv[nj] = wbias[n];
  }
#pragma unroll
  for (int mi = 0; mi < 4; ++mi) {
#pragma unroll
    for (int reg = 0; reg < 16; ++reg) {
      int m = tm0 + mi * 32 + (reg & 3) + 8 * (reg >> 2) + 4 * hl;
      float xs = xscale[m];
      float sx = sumx[m];
      float* crow = C + (size_t)m * NDIM + tn0 + wc * 64 + col32;
#pragma unroll
      for (int nj = 0; nj < 2; ++nj)
        crow[nj * 32] = wsv[nj] * xs * (float)acc[mi][nj][reg] + wbv[nj] * sx;
    }
  }
}

extern "C" void kernel_launch(void* const* d_in, const int* in_sizes, int n_in,
                              void* d_out, int out_size, void* d_ws, size_t ws_size,
                              hipStream_t stream) {
  const float* x      = (const float*)d_in[0];
  const float* weight = (const float*)d_in[1];
  const float* wscale = (const float*)d_in[2];
  const float* wbias  = (const float*)d_in[3];
  float* out = (float*)d_out;

  char* xq  = (char*)d_ws;
  char* wsg = xq + (size_t)MDIM * KDIM;
  float* xscale = (float*)(wsg + (size_t)NDIM * KDIM);
  float* sumx   = xscale + MDIM;

  prep_kernel<<<MDIM + (NDIM * KDIM) / (16 * 256), 256, 0, stream>>>(
      x, weight, xq, wsg, xscale, sumx);
  gemm_bin_i8_2b<<<(MDIM / 128) * (NDIM / 256), 256, 0, stream>>>(
      xq, wsg, wscale, wbias, xscale, sumx, out);
}

// Round 6
// 235.896 us; speedup vs baseline: 1.1516x; 1.1516x over previous
//
#include <hip/hip_runtime.h>
#include <stdint.h>

// BinaryLinearWscales: out[m,n] = wscale[n] * (x @ sign(W)^T)[m,n] + wbias[n] * rowsum(x)[m]
// M = B*S = 4096, N = DOUT = 4096, K = DIN = 4096.
// Round 11: (a) gemm restored to round-8 exactly (best measured: 72 µs);
//           (b) prep rewritten for bandwidth: per-wave x-row ownership
//               (shuffle-only reduce, no LDS, no barriers, x read once into
//               16 float4 regs), grid-stride W sign stream; 2048 blocks x 256.
//   This is a discriminating experiment on the constant ~160 µs of non-gemm
//   time (total - gemm has been 152-161 µs in every round; HBM floor for
//   prep's 160 MB is ~25 µs).

#define MDIM 4096
#define NDIM 4096
#define KDIM 4096

typedef int int4v  __attribute__((ext_vector_type(4)));

__device__ __forceinline__ int pack4_rn(float a, float b, float c, float d, float inv) {
  int ia = __float2int_rn(a * inv) & 0xff;
  int ib = __float2int_rn(b * inv) & 0xff;
  int ic = __float2int_rn(c * inv) & 0xff;
  int id = __float2int_rn(d * inv) & 0xff;
  return ia | (ib << 8) | (ic << 16) | (id << 24);
}

__device__ __forceinline__ int sgn8(float v) {
  return (v > 0.f) ? 1 : ((v < 0.f) ? 0xff : 0);
}

// ---------------- bandwidth-oriented prep ----------------
// blocks [0,1024): x quant. 4 waves/block, one x-row per wave: butterfly-shuffle
//   reduce (no LDS/barriers), row held in 16 float4 regs (single read of x).
// blocks [1024,2048): sign(W) stream, grid-stride, 16 float4 per thread.
#define PREP_XB 1024
#define PREP_WB 1024
__global__ __launch_bounds__(256) void prep_kernel(
    const float* __restrict__ x, const float* __restrict__ w,
    char* __restrict__ xq, char* __restrict__ wsg,
    float* __restrict__ xscale, float* __restrict__ sumx) {
  const int b = blockIdx.x;
  const int tid = threadIdx.x;
  const int lane = tid & 63, wv = tid >> 6;
  if (b < PREP_XB) {
    const int row = b * 4 + wv;
    const float4* xr = (const float4*)(x + (size_t)row * KDIM);
    float4 v[16];
    float s = 0.f, amax = 0.f;
#pragma unroll
    for (int u = 0; u < 16; ++u) {
      v[u] = xr[u * 64 + lane];
      s += v[u].x + v[u].y + v[u].z + v[u].w;
      amax = fmaxf(amax, fmaxf(fmaxf(fabsf(v[u].x), fabsf(v[u].y)),
                               fmaxf(fabsf(v[u].z), fabsf(v[u].w))));
    }
#pragma unroll
    for (int off = 32; off > 0; off >>= 1) {
      s += __shfl_xor(s, off, 64);
      amax = fmaxf(amax, __shfl_xor(amax, off, 64));
    }
    if (lane == 0) {
      sumx[row] = s;
      xscale[row] = amax * (1.f / 127.f);
    }
    const float inv = (amax > 0.f) ? 127.f / amax : 0.f;
    int* xo = (int*)(xq + (size_t)row * KDIM);
#pragma unroll
    for (int u = 0; u < 16; ++u)
      xo[u * 64 + lane] = pack4_rn(v[u].x, v[u].y, v[u].z, v[u].w, inv);
  } else {
    // W: 4M float4 total = 16 sweeps of (1024 blocks x 256 thr)
    const float4* wr = (const float4*)w;
    int* wo = (int*)wsg;
    const size_t i0 = (size_t)(b - PREP_XB) * 256 + tid;
    const size_t stride = (size_t)PREP_WB * 256;
#pragma unroll
    for (int u = 0; u < 16; ++u) {
      size_t i = i0 + (size_t)u * stride;
      float4 vv = wr[i];
      wo[i] = sgn8(vv.x) | (sgn8(vv.y) << 8) | (sgn8(vv.z) << 16) | (sgn8(vv.w) << 24);
    }
  }
}

// ---------------- 256x256 pipelined 8-phase i8 GEMM (32x32x32 MFMA) ----------------
// (round-8 kernel, verbatim — best measured 72 µs, MfmaUtil 40%)
__global__ __launch_bounds__(512, 2) void gemm_bin_i8_pipe(
    const char* __restrict__ A, const char* __restrict__ Bs,
    const float* __restrict__ wscale, const float* __restrict__ wbias,
    const float* __restrict__ xscale, const float* __restrict__ sumx,
    float* __restrict__ C) {
  // A region: [0,64K) = (buf*2+kh)*16384 ; B region: [64K,128K)
  __shared__ __align__(16) char sm[131072];

  const int bm = blockIdx.x >> 4, bn = blockIdx.x & 15;
  const int tm0 = bm * 256, tn0 = bn * 256;
  const int tid = threadIdx.x;
  const int lane = tid & 63, wave = tid >> 6;
  const int col32 = lane & 31, hl = lane >> 5;
  const int wr = wave >> 2, wc = wave & 3;

  typedef int int16v __attribute__((ext_vector_type(16)));
  int16v acc[4][2];
#pragma unroll
  for (int mi = 0; mi < 4; ++mi)
#pragma unroll
    for (int nj = 0; nj < 2; ++nj)
#pragma unroll
      for (int r = 0; r < 16; ++r) acc[mi][nj][r] = 0;

  int4v afA[4], bqA[2], afB[4], bqB[2];

  int aOff[2][4], bOff[2][2];
#pragma unroll
  for (int ks2 = 0; ks2 < 2; ++ks2) {
#pragma unroll
    for (int mi = 0; mi < 4; ++mi) {
      int row = wr * 128 + mi * 32 + col32;
      int sw = (row >> 1) & 3;
      aOff[ks2][mi] = row * 64 + (((ks2 * 2 + hl) ^ sw) & 3) * 16;
    }
#pragma unroll
    for (int nj = 0; nj < 2; ++nj) {
      int row = wc * 64 + nj * 32 + col32;
      int sw = (row >> 1) & 3;
      bOff[ks2][nj] = 65536 + row * 64 + (((ks2 * 2 + hl) ^ sw) & 3) * 16;
    }
  }

  const int u0 = tid, u1 = tid + 512;
  const int r0 = u0 >> 2, r1 = u1 >> 2;
  const int c0 = (u0 & 3) ^ ((r0 >> 1) & 3);
  const int c1 = (u1 & 3) ^ ((r1 >> 1) & 3);
  const char* gA0 = A + (size_t)(tm0 + r0) * KDIM + c0 * 16;
  const char* gA1 = A + (size_t)(tm0 + r1) * KDIM + c1 * 16;
  const char* gB0 = Bs + (size_t)(tn0 + r0) * KDIM + c0 * 16;
  const char* gB1 = Bs + (size_t)(tn0 + r1) * KDIM + c1 * 16;
  const int ldsu0 = tid * 16, ldsu1 = 8192 + tid * 16;

#define STAGE_A(BUF, KH, KOFS)                                                    \
  do {                                                                            \
    const int base_ = ((BUF) * 2 + (KH)) * 16384;                                 \
    __builtin_amdgcn_global_load_lds(                                             \
        (const __attribute__((address_space(1))) void*)(gA0 + (KOFS)),            \
        (__attribute__((address_space(3))) void*)(sm + base_ + ldsu0), 16, 0, 0); \
    __builtin_amdgcn_global_load_lds(                                             \
        (const __attribute__((address_space(1))) void*)(gA1 + (KOFS)),            \
        (__attribute__((address_space(3))) void*)(sm + base_ + ldsu1), 16, 0, 0); \
  } while (0)

#define STAGE_B(BUF, KH, KOFS)                                                    \
  do {                                                                            \
    const int base_ = 65536 + ((BUF) * 2 + (KH)) * 16384;                         \
    __builtin_amdgcn_global_load_lds(                                             \
        (const __attribute__((address_space(1))) void*)(gB0 + (KOFS)),            \
        (__attribute__((address_space(3))) void*)(sm + base_ + ldsu0), 16, 0, 0); \
    __builtin_amdgcn_global_load_lds(                                             \
        (const __attribute__((address_space(1))) void*)(gB1 + (KOFS)),            \
        (__attribute__((address_space(3))) void*)(sm + base_ + ldsu1), 16, 0, 0); \
  } while (0)

#define DSRD(SET, BUF, KS, KS2)                                                   \
  do {                                                                            \
    _Pragma("unroll") for (int mi_ = 0; mi_ < 4; ++mi_)                           \
        af##SET[mi_] =                                                            \
            *(const int4v*)(sm + ((BUF) * 2 + (KS)) * 16384 + aOff[KS2][mi_]);    \
    _Pragma("unroll") for (int nj_ = 0; nj_ < 2; ++nj_)                           \
        bq##SET[nj_] =                                                            \
            *(const int4v*)(sm + ((BUF) * 2 + (KS)) * 16384 + bOff[KS2][nj_]);    \
  } while (0)

#define MFMA8(SET)                                                                \
  do {                                                                            \
    __builtin_amdgcn_s_setprio(1);                                                \
    _Pragma("unroll") for (int mi_ = 0; mi_ < 4; ++mi_)                           \
        _Pragma("unroll") for (int nj_ = 0; nj_ < 2; ++nj_)                       \
            acc[mi_][nj_] = __builtin_amdgcn_mfma_i32_32x32x32_i8(                \
                af##SET[mi_], bq##SET[nj_], acc[mi_][nj_], 0, 0, 0);              \
    __builtin_amdgcn_s_setprio(0);                                                \
  } while (0)

#define WAITL6                                                                    \
  do {                                                                            \
    asm volatile("s_waitcnt lgkmcnt(6)" ::: "memory");                            \
    __builtin_amdgcn_sched_barrier(0);                                            \
  } while (0)
#define WAITL0                                                                    \
  do {                                                                            \
    asm volatile("s_waitcnt lgkmcnt(0)" ::: "memory");                            \
    __builtin_amdgcn_sched_barrier(0);                                            \
  } while (0)

#define BARO __builtin_amdgcn_s_barrier()
#define CK6  asm volatile("s_waitcnt vmcnt(6)\n\ts_barrier" ::: "memory")
#define CK4  asm volatile("s_waitcnt vmcnt(4)\n\ts_barrier" ::: "memory")
#define CK0  asm volatile("s_waitcnt vmcnt(0)\n\ts_barrier" ::: "memory")

#define PHASEP(CSET, NSET, NBUF, NKS, NKS2, STAGEOP, ENDSYNC)                     \
  do {                                                                            \
    DSRD(NSET, NBUF, NKS, NKS2);                                                  \
    STAGEOP;                                                                      \
    WAITL6;                                                                       \
    MFMA8(CSET);                                                                  \
    ENDSYNC;                                                                      \
  } while (0)

#define TILE_MAIN(BUF, TAU)                                                       \
  do {                                                                            \
    PHASEP(A, B, BUF, 0, 1, STAGE_A((BUF) ^ 1, 1, ((TAU) + 1) * 128 + 64), BARO); \
    PHASEP(B, A, BUF, 1, 0, STAGE_B((BUF) ^ 1, 1, ((TAU) + 1) * 128 + 64), BARO); \
    PHASEP(A, B, BUF, 1, 1, STAGE_A(BUF, 0, ((TAU) + 2) * 128), CK6);             \
    PHASEP(B, A, (BUF) ^ 1, 0, 0, STAGE_B(BUF, 0, ((TAU) + 2) * 128), CK4);       \
  } while (0)

  STAGE_A(0, 0, 0);
  STAGE_B(0, 0, 0);
  STAGE_A(0, 1, 64);
  STAGE_B(0, 1, 64);
  STAGE_A(1, 0, 128);
  STAGE_B(1, 0, 128);
  CK4;
  DSRD(A, 0, 0, 0);

#pragma unroll 1
  for (int t = 0; t < 30; t += 2) {
    TILE_MAIN(0, t);
    TILE_MAIN(1, t + 1);
  }

  PHASEP(A, B, 0, 0, 1, STAGE_A(1, 1, 31 * 128 + 64), BARO);
  PHASEP(B, A, 0, 1, 0, STAGE_B(1, 1, 31 * 128 + 64), BARO);
  PHASEP(A, B, 0, 1, 1, (void)0, CK4);
  PHASEP(B, A, 1, 0, 0, (void)0, CK0);
  PHASEP(A, B, 1, 0, 1, (void)0, BARO);
  PHASEP(B, A, 1, 1, 0, (void)0, BARO);
  PHASEP(A, B, 1, 1, 1, (void)0, BARO);
  WAITL0;
  MFMA8(B);

#undef TILE_MAIN
#undef PHASEP
#undef BARO
#undef CK6
#undef CK4
#undef CK0
#undef WAITL6
#undef WAITL0
#undef MFMA8
#undef DSRD
#undef STAGE_A
#undef STAGE_B

  // epilogue: C[m,n] = wscale[n]*xscale[m]*acc + wbias[n]*sumx[m]
  float wsv[2], wbv[2];
#pragma unroll
  for (int nj = 0; nj < 2; ++nj) {
    int n = tn0 + wc * 64 + nj * 32 + col32;
    wsv[nj] = wscale[n];
    wbv[nj] = wbias[n];
  }
#pragma unroll
  for (int mi = 0; mi < 4; ++mi) {
#pragma unroll
    for (int reg = 0; reg < 16; ++reg) {
      int m = tm0 + wr * 128 + mi * 32 + (reg & 3) + 8 * (reg >> 2) + 4 * hl;
      float xs = xscale[m];
      float sx = sumx[m];
      float* crow = C + (size_t)m * NDIM + tn0 + wc * 64 + col32;
#pragma unroll
      for (int nj = 0; nj < 2; ++nj)
        crow[nj * 32] = wsv[nj] * xs * (float)acc[mi][nj][reg] + wbv[nj] * sx;
    }
  }
}

extern "C" void kernel_launch(void* const* d_in, const int* in_sizes, int n_in,
                              void* d_out, int out_size, void* d_ws, size_t ws_size,
                              hipStream_t stream) {
  const float* x      = (const float*)d_in[0];
  const float* weight = (const float*)d_in[1];
  const float* wscale = (const float*)d_in[2];
  const float* wbias  = (const float*)d_in[3];
  float* out = (float*)d_out;

  char* xq  = (char*)d_ws;
  char* wsg = xq + (size_t)MDIM * KDIM;
  float* xscale = (float*)(wsg + (size_t)NDIM * KDIM);
  float* sumx   = xscale + MDIM;

  prep_kernel<<<PREP_XB + PREP_WB, 256, 0, stream>>>(
      x, weight, xq, wsg, xscale, sumx);
  gemm_bin_i8_pipe<<<(MDIM / 256) * (NDIM / 256), 512, 0, stream>>>(
      xq, wsg, wscale, wbias, xscale, sumx, out);
}